// Round 2
// baseline (504.651 us; speedup 1.0000x reference)
//
#include <hip/hip_runtime.h>

// RefWignerRotation: out[n, off + m*d + i, c] = sum_j D^l_n[i,j] * x[n, off + m*d + j, c]
// IRREPS: (l=0,mul=128) rows 0..127 | (l=1,64) rows 128..319 | (l=2,32) rows 320..479 | (l=3,16) rows 480..591
// DIM=592, C=16, N=8192. Memory-bound: 620 MB total traffic, roofline ~98us.
//
// D^l = A(alpha) * B(beta) * A(gamma), with B(beta) entries tabulated as a 7-term
// trig basis (k0, cos b, sin b, cos 2b, sin 2b, cos 3b, sin 3b) — verified round 0.
//
// Round 1 changes:
//  - balanced per-thread mem-op counts (18/20/18 float4 ops vs 20/24/10)
//  - nontemporal loads/stores (pure streaming kernel; avoid cache pollution)
//  - l=0 copy redistributed as fully-coalesced 1024B wave instructions

#define SAMPLE_F 9472      // 592*16 floats per sample

typedef float v4f __attribute__((ext_vector_type(4)));

// 83 D entries: l=1 -> t=0..8 (i*3+j), l=2 -> t=9..33 (9+i*5+j), l=3 -> t=34..82 (34+i*7+j)
__device__ __constant__ float CB[83 * 7] = {
    // ---- l=1 (d=3) ----
    1,0,0,0,0,0,0,
    0,0,0,0,0,0,0,
    0,0,0,0,0,0,0,
    0,0,0,0,0,0,0,
    0,1,0,0,0,0,0,
    0,0,-1,0,0,0,0,
    0,0,0,0,0,0,0,
    0,0,1,0,0,0,0,
    0,1,0,0,0,0,0,
    // ---- l=2 (d=5) ----
    0,1,0,0,0,0,0,
    0,0,1,0,0,0,0,
    0,0,0,0,0,0,0,
    0,0,0,0,0,0,0,
    0,0,0,0,0,0,0,
    0,0,-1,0,0,0,0,
    0,1,0,0,0,0,0,
    0,0,0,0,0,0,0,
    0,0,0,0,0,0,0,
    0,0,0,0,0,0,0,
    0,0,0,0,0,0,0,
    0,0,0,0,0,0,0,
    0.25f,0,0,0.75f,0,0,0,
    0,0,0,0,-0.8660254037844387f,0,0,
    0.4330127018922193f,0,0,-0.4330127018922193f,0,0,0,
    0,0,0,0,0,0,0,
    0,0,0,0,0,0,0,
    0,0,0,0,0.8660254037844387f,0,0,
    0,0,0,1,0,0,0,
    0,0,0,0,-0.5f,0,0,
    0,0,0,0,0,0,0,
    0,0,0,0,0,0,0,
    0.4330127018922193f,0,0,-0.4330127018922193f,0,0,0,
    0,0,0,0,0.5f,0,0,
    0.75f,0,0,0.25f,0,0,0,
    // ---- l=3 (d=7) ----
    0.625f,0,0,0.375f,0,0,0,
    0,0,0,0,0.6123724356957945f,0,0,
    0.4841229182759271f,0,0,-0.4841229182759271f,0,0,0,
    0,0,0,0,0,0,0, 0,0,0,0,0,0,0, 0,0,0,0,0,0,0, 0,0,0,0,0,0,0,
    0,0,0,0,-0.6123724356957945f,0,0,
    0,0,0,1,0,0,0,
    0,0,0,0,0.7905694150420949f,0,0,
    0,0,0,0,0,0,0, 0,0,0,0,0,0,0, 0,0,0,0,0,0,0, 0,0,0,0,0,0,0,
    0.4841229182759271f,0,0,-0.4841229182759271f,0,0,0,
    0,0,0,0,-0.7905694150420949f,0,0,
    0.375f,0,0,0.625f,0,0,0,
    0,0,0,0,0,0,0, 0,0,0,0,0,0,0, 0,0,0,0,0,0,0, 0,0,0,0,0,0,0,
    0,0,0,0,0,0,0, 0,0,0,0,0,0,0, 0,0,0,0,0,0,0,
    0,0.375f,0,0,0,0.625f,0,
    0,0,-0.1530931089239487f,0,0,0,-0.7654655446197435f,
    0,0.4841229182759271f,0,0,0,-0.4841229182759271f,0,
    0,0,-0.5929270612815711f,0,0,0,0.1976423537605237f,
    0,0,0,0,0,0,0, 0,0,0,0,0,0,0, 0,0,0,0,0,0,0,
    0,0,0.1530931089239487f,0,0,0,0.7654655446197435f,
    0,0.0625f,0,0,0,0.9375f,0,
    0,0,0.1976423537605237f,0,0,0,-0.5929270612815711f,
    0,0.2420614591379636f,0,0,0,-0.2420614591379636f,0,
    0,0,0,0,0,0,0, 0,0,0,0,0,0,0, 0,0,0,0,0,0,0,
    0,0.4841229182759271f,0,0,0,-0.4841229182759271f,0,
    0,0,-0.1976423537605237f,0,0,0,0.5929270612815711f,
    0,0.625f,0,0,0,0.375f,0,
    0,0,-0.7654655446197435f,0,0,0,-0.1530931089239487f,
    0,0,0,0,0,0,0, 0,0,0,0,0,0,0, 0,0,0,0,0,0,0,
    0,0,0.5929270612815711f,0,0,0,-0.1976423537605237f,
    0,0.2420614591379636f,0,0,0,-0.2420614591379636f,0,
    0,0,0.7654655446197435f,0,0,0,0.1530931089239487f,
    0,0.9375f,0,0,0,0.0625f,0,
};

__global__ __launch_bounds__(256) void wigner_kernel(
    const float* __restrict__ x, const float* __restrict__ alpha,
    const float* __restrict__ beta, const float* __restrict__ gamma,
    float* __restrict__ out)
{
    __shared__ float sD[84];
    const int n = blockIdx.x;
    const int t = threadIdx.x;

    // ---------------- Phase 1: D entries -> LDS (threads 0..82) ----------------
    if (t < 83) {
        int l, i, j, base;
        if (t < 9)       { l = 1; base = 0;  int e = t;      i = e / 3; j = e - i * 3; }
        else if (t < 34) { l = 2; base = 9;  int e = t - 9;  i = e / 5; j = e - i * 5; }
        else             { l = 3; base = 34; int e = t - 34; i = e / 7; j = e - i * 7; }
        const int d = 2 * l + 1;

        const float a = alpha[n], b = beta[n], g = gamma[n];
        float cb1, sb1;
        __sincosf(b, &sb1, &cb1);
        const float cb2 = cb1 * cb1 - sb1 * sb1, sb2 = 2.f * sb1 * cb1;
        const float cb3 = cb2 * cb1 - sb2 * sb1, sb3 = sb2 * cb1 + cb2 * sb1;

        auto Bent = [&](int p, int q) -> float {
            const float* cc = &CB[(base + p * d + q) * 7];
            return cc[0] + cc[1] * cb1 + cc[2] * sb1 + cc[3] * cb2
                 + cc[4] * sb2 + cc[5] * cb3 + cc[6] * sb3;
        };

        const int ip = 2 * l - i, jp = 2 * l - j;
        float u, v;
        {
            const int mu = (i < l) ? (l - i) : (i - l);
            float sa, ca;
            __sincosf((float)mu * a, &sa, &ca);
            if (i < l)      { u = ca;  v = sa; }
            else if (i == l){ u = 1.f; v = 0.f; }
            else            { u = ca;  v = -sa; }
        }
        float p_, q_;
        {
            const int mu = (j < l) ? (l - j) : (j - l);
            float sg, cg;
            __sincosf((float)mu * g, &sg, &cg);
            if (j < l)      { p_ = cg;  q_ = -sg; }
            else if (j == l){ p_ = 1.f; q_ = 0.f; }
            else            { p_ = cg;  q_ = sg; }
        }
        const float Mij  = u * Bent(i, j)  + v * Bent(ip, j);
        const float Mijp = u * Bent(i, jp) + v * Bent(ip, jp);
        sD[t] = p_ * Mij + q_ * Mijp;
    }
    __syncthreads();

    // ---------------- Phase 2: streaming apply ----------------
    // Per-thread float4 mem-ops: t0..127: 18, t128..191: 20, t192..255: 18.
    const v4f* __restrict__ xs4 = (const v4f*)(x + (size_t)n * SAMPLE_F);
    v4f* __restrict__ os4 = (v4f*)(out + (size_t)n * SAMPLE_F);

    // l=1: 64 m-blocks x 4 float4-channels = 256 units (all threads)
    {
        const int m = t >> 2, c4 = t & 3;
        const int r4 = 512 + 12 * m + c4;  // (128 + 3m)*4 + c4
        const v4f x0 = __builtin_nontemporal_load(xs4 + r4);
        const v4f x1 = __builtin_nontemporal_load(xs4 + r4 + 4);
        const v4f x2 = __builtin_nontemporal_load(xs4 + r4 + 8);
        const v4f y0 = sD[0] * x0 + sD[1] * x1 + sD[2] * x2;
        const v4f y1 = sD[3] * x0 + sD[4] * x1 + sD[5] * x2;
        const v4f y2 = sD[6] * x0 + sD[7] * x1 + sD[8] * x2;
        __builtin_nontemporal_store(y0, os4 + r4);
        __builtin_nontemporal_store(y1, os4 + r4 + 4);
        __builtin_nontemporal_store(y2, os4 + r4 + 8);
    }

    if (t < 128) {
        // l=2: 32 m-blocks x 4 = 128 units
        const int m = t >> 2, c4 = t & 3;
        const int r4 = 1280 + 20 * m + c4;  // (320 + 5m)*4 + c4
        v4f xv[5];
        #pragma unroll
        for (int j = 0; j < 5; ++j) xv[j] = __builtin_nontemporal_load(xs4 + r4 + 4 * j);
        #pragma unroll
        for (int i = 0; i < 5; ++i) {
            v4f y = sD[9 + i * 5] * xv[0];
            #pragma unroll
            for (int j = 1; j < 5; ++j) y += sD[9 + i * 5 + j] * xv[j];
            __builtin_nontemporal_store(y, os4 + r4 + 4 * i);
        }
        // l=0 share: 1 float4 copy (indices 0..127, fully coalesced)
        __builtin_nontemporal_store(__builtin_nontemporal_load(xs4 + t), os4 + t);
    } else if (t < 192) {
        // l=3: 16 m-blocks x 4 = 64 units (one wave)
        const int e = t - 128;
        const int m = e >> 2, c4 = e & 3;
        const int r4 = 1920 + 28 * m + c4;  // (480 + 7m)*4 + c4
        v4f xv[7];
        #pragma unroll
        for (int j = 0; j < 7; ++j) xv[j] = __builtin_nontemporal_load(xs4 + r4 + 4 * j);
        #pragma unroll
        for (int i = 0; i < 7; ++i) {
            v4f y = sD[34 + i * 7] * xv[0];
            #pragma unroll
            for (int j = 1; j < 7; ++j) y += sD[34 + i * 7 + j] * xv[j];
            __builtin_nontemporal_store(y, os4 + r4 + 4 * i);
        }
    } else {
        // l=0 share: 6 float4 copies each (indices 128..511), each k-step is a
        // contiguous 1024B wave64 access
        const int e = t - 192;
        #pragma unroll
        for (int k = 0; k < 6; ++k) {
            const int f = 128 + 64 * k + e;
            __builtin_nontemporal_store(__builtin_nontemporal_load(xs4 + f), os4 + f);
        }
    }
}

extern "C" void kernel_launch(void* const* d_in, const int* in_sizes, int n_in,
                              void* d_out, int out_size, void* d_ws, size_t ws_size,
                              hipStream_t stream) {
    const float* x     = (const float*)d_in[0];
    const float* alpha = (const float*)d_in[1];
    const float* beta  = (const float*)d_in[2];
    const float* gamma = (const float*)d_in[3];
    float* out = (float*)d_out;
    const int n = in_sizes[1];  // 8192 samples
    wigner_kernel<<<dim3(n), dim3(256), 0, stream>>>(x, alpha, beta, gamma, out);
}